// Round 1
// baseline (39.930 us; speedup 1.0000x reference)
//
#include <hip/hip_runtime.h>

// KAN layer: out[bs,o] = sum_{i,n} tanh(h[i,n,o]*x[bs,i] + b[i,n,o]) * w[i,n,o]
// B=2, S=1024 -> BS=2048 ; I=64, N=16, O=64.
//
// Strategy:
//  - lane = o (64 lanes = 64 outputs), coalesced dword loads of h/b/w.
//  - each block handles 4 consecutive bs positions (held in registers),
//    its 4 waves split the i-range (16 i's each) -> 512 blocks, 2048 waves.
//  - tanh(z) = 1 - 2/(exp2(K*z)+1), K = 2*log2(e). Per element:
//    fma, v_exp_f32, add, v_rcp_f32, fma.  Sum of w hoisted per-wave.
//  - LDS reduction across the 4 waves; exact 131072 coalesced stores.

#define BS_PER_BLOCK 4
#define WAVES 4
#define I_PER_WAVE 16   // 64 / WAVES
#define N_DIM 16
#define O_DIM 64

__global__ __launch_bounds__(256, 2)
void kan_kernel(const float* __restrict__ x,
                const float* __restrict__ w,
                const float* __restrict__ h,
                const float* __restrict__ b,
                float* __restrict__ out) {
    const int tid  = threadIdx.x;
    const int o    = tid & 63;
    const int wave = tid >> 6;                 // 0..3 -> i-quarter
    const int bs0  = blockIdx.x * BS_PER_BLOCK;

    constexpr float K = 2.88539008177792681472f;  // 2 * log2(e)

    float acc0 = 0.f, acc1 = 0.f, acc2 = 0.f, acc3 = 0.f;
    float accw = 0.f;  // sum of w over this wave's (i,n) range (bs-independent)

    const int i_begin = wave * I_PER_WAVE;

    for (int ii = 0; ii < I_PER_WAVE; ++ii) {
        const int i = i_begin + ii;
        // x values for the 4 bs positions (wave-uniform addresses)
        const float x0 = x[(bs0 + 0) * 64 + i];
        const float x1 = x[(bs0 + 1) * 64 + i];
        const float x2 = x[(bs0 + 2) * 64 + i];
        const float x3 = x[(bs0 + 3) * 64 + i];

        const float* __restrict__ hp = h + (i * N_DIM) * O_DIM + o;
        const float* __restrict__ bp = b + (i * N_DIM) * O_DIM + o;
        const float* __restrict__ wp = w + (i * N_DIM) * O_DIM + o;

#pragma unroll
        for (int n = 0; n < N_DIM; ++n) {
            const float hv = hp[n * O_DIM];
            const float bv = bp[n * O_DIM];
            const float wv = wp[n * O_DIM];

            const float hk  = hv * K;
            const float bk  = bv * K;
            const float wm2 = -2.0f * wv;
            accw += wv;

            // tanh(z)*w = w - 2w / (exp2(K*z) + 1)
            float t0 = __builtin_amdgcn_exp2f(fmaf(hk, x0, bk));
            float t1 = __builtin_amdgcn_exp2f(fmaf(hk, x1, bk));
            float t2 = __builtin_amdgcn_exp2f(fmaf(hk, x2, bk));
            float t3 = __builtin_amdgcn_exp2f(fmaf(hk, x3, bk));

            float r0 = __builtin_amdgcn_rcpf(t0 + 1.0f);
            float r1 = __builtin_amdgcn_rcpf(t1 + 1.0f);
            float r2 = __builtin_amdgcn_rcpf(t2 + 1.0f);
            float r3 = __builtin_amdgcn_rcpf(t3 + 1.0f);

            acc0 = fmaf(wm2, r0, acc0);
            acc1 = fmaf(wm2, r1, acc1);
            acc2 = fmaf(wm2, r2, acc2);
            acc3 = fmaf(wm2, r3, acc3);
        }
    }

    // partial for (bs0+j, o) from this wave = acc_j + accw
    __shared__ float lds[WAVES][BS_PER_BLOCK][O_DIM];
    lds[wave][0][o] = acc0 + accw;
    lds[wave][1][o] = acc1 + accw;
    lds[wave][2][o] = acc2 + accw;
    lds[wave][3][o] = acc3 + accw;
    __syncthreads();

    // 256 threads -> 256 outputs: j = tid>>6 (bs offset), oo = tid&63
    const int j  = tid >> 6;
    const int oo = tid & 63;
    float v = lds[0][j][oo] + lds[1][j][oo] + lds[2][j][oo] + lds[3][j][oo];
    out[(bs0 + j) * 64 + oo] = v;
}

extern "C" void kernel_launch(void* const* d_in, const int* in_sizes, int n_in,
                              void* d_out, int out_size, void* d_ws, size_t ws_size,
                              hipStream_t stream) {
    // setup_inputs order: x, w, h, b
    const float* x = (const float*)d_in[0];
    const float* w = (const float*)d_in[1];
    const float* h = (const float*)d_in[2];
    const float* b = (const float*)d_in[3];
    float* out = (float*)d_out;

    const int BS = 2 * 1024;                       // B*S
    dim3 grid(BS / BS_PER_BLOCK);                  // 512 blocks
    dim3 block(256);                               // 4 waves
    kan_kernel<<<grid, block, 0, stream>>>(x, w, h, b, out);
}

// Round 2
// 34.287 us; speedup vs baseline: 1.1646x; 1.1646x over previous
//
#include <hip/hip_runtime.h>

// KAN layer: out[bs,o] = sum_{i,n} tanh(h[i,n,o]*x[bs,i] + b[i,n,o]) * w[i,n,o]
// B=2, S=1024 -> BS=2048 ; I=64, N=16, O=64.
//
// Round 1 -> 2 change: occupancy 2 -> 8 waves/SIMD.
//  - block = 1024 threads (16 waves), grid = 512 blocks (one per 4 bs positions)
//    -> 8192 waves = 32 waves/CU = 8/SIMD, exactly 2 blocks/CU, no tail.
//  - lane = o (coalesced dword loads of h/b/w; 768 KB total -> L2-resident).
//  - each wave: 4 i's x 16 n, 4 independent bs-chains for ILP.
//  - tanh(z)*w = w - 2w/(exp2(K*z)+1), K = 2*log2(e); x pre-scaled by K
//    so per (i,n): only bk mul + wm2 mul + accw add besides the element chain.

#define BS_PER_BLOCK 4
#define WAVES 16
#define I_PER_WAVE 4    // 64 / WAVES
#define N_DIM 16
#define O_DIM 64

__global__ __launch_bounds__(1024, 2)
void kan_kernel(const float* __restrict__ x,
                const float* __restrict__ w,
                const float* __restrict__ h,
                const float* __restrict__ b,
                float* __restrict__ out) {
    const int tid  = threadIdx.x;
    const int o    = tid & 63;
    const int wave = tid >> 6;                 // 0..15 -> i-slice
    const int bs0  = blockIdx.x * BS_PER_BLOCK;

    constexpr float K = 2.88539008177792681472f;  // 2 * log2(e)

    float acc0 = 0.f, acc1 = 0.f, acc2 = 0.f, acc3 = 0.f;
    float accw = 0.f;  // sum of w over this wave's (i,n) range (bs-independent)

    const int i_begin = wave * I_PER_WAVE;

    for (int ii = 0; ii < I_PER_WAVE; ++ii) {
        const int i = i_begin + ii;
        // x values for the 4 bs positions (wave-uniform -> scalar loads),
        // pre-scaled by K so the element chain is fmaf(hv, xK, bk).
        const float x0 = x[(bs0 + 0) * 64 + i] * K;
        const float x1 = x[(bs0 + 1) * 64 + i] * K;
        const float x2 = x[(bs0 + 2) * 64 + i] * K;
        const float x3 = x[(bs0 + 3) * 64 + i] * K;

        const float* __restrict__ hp = h + (i * N_DIM) * O_DIM + o;
        const float* __restrict__ bp = b + (i * N_DIM) * O_DIM + o;
        const float* __restrict__ wp = w + (i * N_DIM) * O_DIM + o;

#pragma unroll
        for (int n = 0; n < N_DIM; ++n) {
            const float hv = hp[n * O_DIM];
            const float bv = bp[n * O_DIM];
            const float wv = wp[n * O_DIM];

            const float bk  = bv * K;
            const float wm2 = -2.0f * wv;
            accw += wv;

            // tanh(z)*w = w - 2w / (exp2(K*z) + 1)
            float t0 = __builtin_amdgcn_exp2f(fmaf(hv, x0, bk));
            float t1 = __builtin_amdgcn_exp2f(fmaf(hv, x1, bk));
            float t2 = __builtin_amdgcn_exp2f(fmaf(hv, x2, bk));
            float t3 = __builtin_amdgcn_exp2f(fmaf(hv, x3, bk));

            float r0 = __builtin_amdgcn_rcpf(t0 + 1.0f);
            float r1 = __builtin_amdgcn_rcpf(t1 + 1.0f);
            float r2 = __builtin_amdgcn_rcpf(t2 + 1.0f);
            float r3 = __builtin_amdgcn_rcpf(t3 + 1.0f);

            acc0 = fmaf(wm2, r0, acc0);
            acc1 = fmaf(wm2, r1, acc1);
            acc2 = fmaf(wm2, r2, acc2);
            acc3 = fmaf(wm2, r3, acc3);
        }
    }

    // partial for (bs0+j, o) from this wave = acc_j + accw
    __shared__ float lds[WAVES][BS_PER_BLOCK][O_DIM];
    lds[wave][0][o] = acc0 + accw;
    lds[wave][1][o] = acc1 + accw;
    lds[wave][2][o] = acc2 + accw;
    lds[wave][3][o] = acc3 + accw;
    __syncthreads();

    // first 256 threads produce the 4*64 outputs
    if (tid < BS_PER_BLOCK * O_DIM) {
        const int j  = tid >> 6;
        const int oo = tid & 63;
        float v = 0.f;
#pragma unroll
        for (int wv = 0; wv < WAVES; ++wv) v += lds[wv][j][oo];
        out[(bs0 + j) * 64 + oo] = v;
    }
}

extern "C" void kernel_launch(void* const* d_in, const int* in_sizes, int n_in,
                              void* d_out, int out_size, void* d_ws, size_t ws_size,
                              hipStream_t stream) {
    // setup_inputs order: x, w, h, b
    const float* x = (const float*)d_in[0];
    const float* w = (const float*)d_in[1];
    const float* h = (const float*)d_in[2];
    const float* b = (const float*)d_in[3];
    float* out = (float*)d_out;

    const int BS = 2 * 1024;                       // B*S
    dim3 grid(BS / BS_PER_BLOCK);                  // 512 blocks
    dim3 block(WAVES * 64);                        // 1024 threads = 16 waves
    kan_kernel<<<grid, block, 0, stream>>>(x, w, h, b, out);
}